// Round 1
// baseline (536.534 us; speedup 1.0000x reference)
//
#include <hip/hip_runtime.h>
#include <math.h>

// Problem constants (from reference: image [4,1,128,256,256] fp32)
namespace {
constexpr int B  = 4;
constexpr int D  = 128;
constexpr int H  = 256;
constexpr int W  = 256;
constexpr int TH = 16;   // tile height (H)
constexpr int TW = 64;   // tile width  (W)
constexpr int CH = 32;   // depth chunk per block
constexpr int RS = 68;   // raw plane row stride (floats), 16B-aligned rows
constexpr int AS = 68;   // a/b row stride
constexpr int PS = 68;   // U/V/T plane row stride
}

// Per-component 3-tap helpers
#define SMOOTH3(o, p0, p1, p2) \
  o.x = fmaf(2.f, p1.x, p0.x + p2.x); \
  o.y = fmaf(2.f, p1.y, p0.y + p2.y); \
  o.z = fmaf(2.f, p1.z, p0.z + p2.z); \
  o.w = fmaf(2.f, p1.w, p0.w + p2.w);
#define DIFF3(o, p0, p2) \
  o.x = p2.x - p0.x; o.y = p2.y - p0.y; o.z = p2.z - p0.z; o.w = p2.w - p0.w;

__global__ __launch_bounds__(256)
void sobel_fused(const float* __restrict__ img, float* __restrict__ out) {
  // LDS: raw haloed plane, W-pass intermediates, 3-plane circular U/V/T
  __shared__ float raw[18 * RS];        // rows h0-1..h0+16, cols w0-1..w0+64
  __shared__ float sa[18 * AS];         // S_W * x  (per row)
  __shared__ float sb[18 * AS];         // D_W * x
  __shared__ float sU[3][TH * PS];      // S_H S_W
  __shared__ float sV[3][TH * PS];      // S_H D_W
  __shared__ float sT[3][TH * PS];      // D_H S_W

  const int t  = threadIdx.x;
  const int w0 = blockIdx.x * TW;
  const int h0 = blockIdx.y * TH;
  const int bz = blockIdx.z;
  const int batch = bz >> 2;            // D/CH = 4 chunks per batch
  const int d0    = (bz & 3) * CH;

  const int r  = t >> 4;                // 0..15 : row within tile
  const int cg = (t & 15) << 2;         // 0,4,...,60 : col group (4 cols)

  const float* imgB = img + (size_t)batch * (D * H * W);
  float* out0 = out + (size_t)batch * (size_t)(2 * D * H * W);
  float* out1 = out0 + (size_t)(D * H * W);

  for (int j = 0; j <= CH + 1; ++j) {
    const int p = d0 + j - 1;                 // input plane loaded this iter
    const bool pin = (p >= 0) && (p < D);
    const bool wr0 = (j >= 1) && (j <= CH);   // plane p belongs to this chunk

    // ---- Phase 1: stage haloed plane into LDS; fuse channel-0 copy ----
    #pragma unroll
    for (int i = 0; i < 5; ++i) {
      int idx = t + i * 256;
      if (idx < 18 * 66) {
        int rr = idx / 66;
        int cc = idx - rr * 66;
        int gh = h0 + rr - 1;
        int gw = w0 + cc - 1;
        float v = 0.f;
        if (pin && (unsigned)gh < (unsigned)H && (unsigned)gw < (unsigned)W)
          v = imgB[((size_t)p * H + gh) * W + gw];
        raw[rr * RS + cc] = v;
        // channel 0 = identity copy, written once per interior voxel
        if (wr0 && rr >= 1 && rr <= TH && cc >= 1 && cc <= TW)
          out0[((size_t)p * H + gh) * W + gw] = v;
      }
    }
    __syncthreads();

    // ---- Phase 2: W-pass (rows r, plus rows 16/17 handled by r<2) ----
    {
      int rr = r;
      #pragma unroll
      for (int pass = 0; pass < 2; ++pass) {
        if (pass == 1) {
          if (r >= 2) break;
          rr = r + 16;
        }
        const float* rp = &raw[rr * RS + cg];
        float4 q = *(const float4*)rp;            // cols cg..cg+3 (rel)
        float2 q2 = *(const float2*)(rp + 4);     // cols cg+4..cg+5
        float x0 = q.x, x1 = q.y, x2 = q.z, x3 = q.w, x4 = q2.x, x5 = q2.y;
        float4 av, bv;
        av.x = fmaf(2.f, x1, x0 + x2);
        av.y = fmaf(2.f, x2, x1 + x3);
        av.z = fmaf(2.f, x3, x2 + x4);
        av.w = fmaf(2.f, x4, x3 + x5);
        bv.x = x2 - x0; bv.y = x3 - x1; bv.z = x4 - x2; bv.w = x5 - x3;
        *(float4*)&sa[rr * AS + cg] = av;
        *(float4*)&sb[rr * AS + cg] = bv;
      }
    }
    __syncthreads();

    // ---- Phase 3: H-pass -> U/V/T circular slot j%3 ----
    {
      const int slot = j % 3;
      float4 a0 = *(const float4*)&sa[(r    ) * AS + cg];
      float4 a1 = *(const float4*)&sa[(r + 1) * AS + cg];
      float4 a2 = *(const float4*)&sa[(r + 2) * AS + cg];
      float4 b0 = *(const float4*)&sb[(r    ) * AS + cg];
      float4 b1 = *(const float4*)&sb[(r + 1) * AS + cg];
      float4 b2 = *(const float4*)&sb[(r + 2) * AS + cg];
      float4 U, V, T;
      SMOOTH3(U, a0, a1, a2);
      DIFF3(T, a0, a2);
      SMOOTH3(V, b0, b1, b2);
      *(float4*)&sU[slot][r * PS + cg] = U;
      *(float4*)&sV[slot][r * PS + cg] = V;
      *(float4*)&sT[slot][r * PS + cg] = T;
    }
    __syncthreads();

    // ---- Phase 4: D-combination + magnitude, write channel 1 ----
    if (j >= 2) {
      const int dout = d0 + j - 2;
      const int s0 = (j - 2) % 3, s1 = (j - 1) % 3, s2 = j % 3;
      float4 v0 = *(const float4*)&sV[s0][r * PS + cg];
      float4 v1 = *(const float4*)&sV[s1][r * PS + cg];
      float4 v2 = *(const float4*)&sV[s2][r * PS + cg];
      float4 t0 = *(const float4*)&sT[s0][r * PS + cg];
      float4 t1 = *(const float4*)&sT[s1][r * PS + cg];
      float4 t2 = *(const float4*)&sT[s2][r * PS + cg];
      float4 u0 = *(const float4*)&sU[s0][r * PS + cg];
      float4 u2 = *(const float4*)&sU[s2][r * PS + cg];
      float4 gx, gy, gz, m;
      SMOOTH3(gx, v0, v1, v2);   // Gx = S_D (S_H D_W)
      SMOOTH3(gy, t0, t1, t2);   // Gy = S_D (D_H S_W)
      DIFF3(gz, u0, u2);         // Gz = D_D (S_H S_W)
      m.x = sqrtf(fmaf(gx.x, gx.x, fmaf(gy.x, gy.x, fmaf(gz.x, gz.x, 1e-8f))));
      m.y = sqrtf(fmaf(gx.y, gx.y, fmaf(gy.y, gy.y, fmaf(gz.y, gz.y, 1e-8f))));
      m.z = sqrtf(fmaf(gx.z, gx.z, fmaf(gy.z, gy.z, fmaf(gz.z, gz.z, 1e-8f))));
      m.w = sqrtf(fmaf(gx.w, gx.w, fmaf(gy.w, gy.w, fmaf(gz.w, gz.w, 1e-8f))));
      *(float4*)&out1[((size_t)dout * H + (h0 + r)) * W + (w0 + cg)] = m;
    }
  }
}

extern "C" void kernel_launch(void* const* d_in, const int* in_sizes, int n_in,
                              void* d_out, int out_size, void* d_ws, size_t ws_size,
                              hipStream_t stream) {
  const float* img = (const float*)d_in[0];
  float* out = (float*)d_out;
  dim3 grid(W / TW, H / TH, B * (D / CH));   // (4, 16, 16) = 1024 blocks
  sobel_fused<<<grid, dim3(256), 0, stream>>>(img, out);
}

// Round 2
// 378.609 us; speedup vs baseline: 1.4171x; 1.4171x over previous
//
#include <hip/hip_runtime.h>
#include <math.h>

// Problem: image [4,1,128,256,256] fp32 -> out [4,2,128,256,256]
//   ch0 = copy(image); ch1 = |sobel3d(image)| (separable s=[1,2,1], d=[-1,0,1])
namespace {
constexpr int B  = 4;
constexpr int D  = 128;
constexpr int H  = 256;
constexpr int W  = 256;
constexpr int TH = 16;   // tile height
constexpr int TW = 64;   // tile width
constexpr int CH = 32;   // depth chunk per block
constexpr int AS = 68;   // sa/sb row stride (floats)
}

#define SMOOTH3(o, p0, p1, p2) \
  o.x = fmaf(2.f, p1.x, p0.x + p2.x); \
  o.y = fmaf(2.f, p1.y, p0.y + p2.y); \
  o.z = fmaf(2.f, p1.z, p0.z + p2.z); \
  o.w = fmaf(2.f, p1.w, p0.w + p2.w);
#define DIFF3(o, p0, p2) \
  o.x = p2.x - p0.x; o.y = p2.y - p0.y; o.z = p2.z - p0.z; o.w = p2.w - p0.w;

__global__ __launch_bounds__(256, 4)
void sobel_fused(const float* __restrict__ img, float* __restrict__ out) {
  // W-pass intermediates only; double-buffered by plane parity -> 1 barrier/plane
  __shared__ float sa[2][18 * AS];   // S_W * x, rows h0-1 .. h0+16
  __shared__ float sb[2][18 * AS];   // D_W * x

  const int t  = threadIdx.x;
  const int r  = t >> 4;              // 0..15 row in tile
  const int cg = (t & 15) << 2;       // 0,4,..,60 col group
  const int w0 = blockIdx.x * TW;
  const int h0 = blockIdx.y * TH;
  const int bz = blockIdx.z;
  const int batch = bz >> 2;          // D/CH = 4 chunks per batch
  const int d0    = (bz & 3) * CH;

  const float* imgB = img + (size_t)batch * ((size_t)D * H * W);
  float* out0 = out + (size_t)batch * ((size_t)2 * D * H * W);
  float* out1 = out0 + (size_t)D * H * W;

  // per-thread 3-plane circular buffers (registers)
  float4 z4 = {0.f, 0.f, 0.f, 0.f};
  float4 U0 = z4, U1 = z4, U2 = z4;   // S_H S_W
  float4 V0 = z4, V1 = z4, V2 = z4;   // S_H D_W
  float4 T0 = z4, T1 = z4, T2 = z4;   // D_H S_W

  for (int j = 0; j <= CH + 1; ++j) {
    const int p = d0 + j - 1;                 // input plane this iter
    const bool pin = (p >= 0) && (p < D);
    const bool wr0 = (j >= 1) && (j <= CH);   // p is an output plane of chunk
    const int buf = j & 1;

    // ---- Phase A: W-pass straight from global (rows r, plus 16/17 by r<2) ----
    #pragma unroll
    for (int pass = 0; pass < 2; ++pass) {
      int rr;
      if (pass == 0) rr = r;
      else { if (r >= 2) break; rr = r + 16; }
      const int gh = h0 + rr - 1;
      const bool rowIn = pin && ((unsigned)gh < (unsigned)H);
      float4 x = z4; float xm = 0.f, xp = 0.f;
      if (rowIn) {
        const float* rp = imgB + ((size_t)p * H + gh) * W + (w0 + cg);
        x = *(const float4*)rp;                 // aligned, coalesced
        if (w0 + cg > 0)     xm = rp[-1];       // L1-hit neighbor
        if (w0 + cg + 4 < W) xp = rp[4];
      }
      float4 av, bv;
      av.x = fmaf(2.f, x.x, xm  + x.y);
      av.y = fmaf(2.f, x.y, x.x + x.z);
      av.z = fmaf(2.f, x.z, x.y + x.w);
      av.w = fmaf(2.f, x.w, x.z + xp);
      bv.x = x.y - xm; bv.y = x.z - x.x; bv.z = x.w - x.y; bv.w = xp - x.z;
      *(float4*)&sa[buf][rr * AS + cg] = av;
      *(float4*)&sb[buf][rr * AS + cg] = bv;
      // fused channel-0 copy: rows h0..h0+15 are rr=1..16's loaded rows
      if (wr0 && rowIn && rr >= 1 && rr <= 16)
        *(float4*)&out0[((size_t)p * H + gh) * W + (w0 + cg)] = x;
    }
    __syncthreads();

    // ---- Phase B: H-pass -> register circular buffers ----
    float4 a0 = *(const float4*)&sa[buf][(r    ) * AS + cg];
    float4 a1 = *(const float4*)&sa[buf][(r + 1) * AS + cg];
    float4 a2 = *(const float4*)&sa[buf][(r + 2) * AS + cg];
    float4 b0 = *(const float4*)&sb[buf][(r    ) * AS + cg];
    float4 b1 = *(const float4*)&sb[buf][(r + 1) * AS + cg];
    float4 b2 = *(const float4*)&sb[buf][(r + 2) * AS + cg];
    float4 Un, Vn, Tn;
    SMOOTH3(Un, a0, a1, a2);
    DIFF3(Tn, a0, a2);
    SMOOTH3(Vn, b0, b1, b2);
    U0 = U1; U1 = U2; U2 = Un;
    V0 = V1; V1 = V2; V2 = Vn;
    T0 = T1; T1 = T2; T2 = Tn;

    // ---- Phase C: D-combination + magnitude (pure registers) ----
    if (j >= 2) {
      const int dout = d0 + j - 2;
      float4 gx, gy, gz, m;
      SMOOTH3(gx, V0, V1, V2);   // Gx = S_D (S_H D_W)
      SMOOTH3(gy, T0, T1, T2);   // Gy = S_D (D_H S_W)
      DIFF3(gz, U0, U2);         // Gz = D_D (S_H S_W)
      m.x = sqrtf(fmaf(gx.x, gx.x, fmaf(gy.x, gy.x, fmaf(gz.x, gz.x, 1e-8f))));
      m.y = sqrtf(fmaf(gx.y, gx.y, fmaf(gy.y, gy.y, fmaf(gz.y, gz.y, 1e-8f))));
      m.z = sqrtf(fmaf(gx.z, gx.z, fmaf(gy.z, gy.z, fmaf(gz.z, gz.z, 1e-8f))));
      m.w = sqrtf(fmaf(gx.w, gx.w, fmaf(gy.w, gy.w, fmaf(gz.w, gz.w, 1e-8f))));
      *(float4*)&out1[((size_t)dout * H + (h0 + r)) * W + (w0 + cg)] = m;
    }
  }
}

extern "C" void kernel_launch(void* const* d_in, const int* in_sizes, int n_in,
                              void* d_out, int out_size, void* d_ws, size_t ws_size,
                              hipStream_t stream) {
  const float* img = (const float*)d_in[0];
  float* out = (float*)d_out;
  dim3 grid(W / TW, H / TH, B * (D / CH));   // (4, 16, 16) = 1024 blocks
  sobel_fused<<<grid, dim3(256), 0, stream>>>(img, out);
}